// Round 1
// baseline (390.381 us; speedup 1.0000x reference)
//
#include <hip/hip_runtime.h>
#include <hip/hip_bf16.h>
#include <math.h>

// B=32, S=1, DIM=2048, NH=32, NKV=8, HD=64, L=2048, START_POS=2047.
// Inputs float32. OUTPUT float32.
#define NQKV 3072

__device__ __forceinline__ int read_sp(const int* spp) {
  if (!spp) return 2047;
  int raw = spp[0];
  if (raw >= 0 && raw < 2048) return raw;
  union { int i; float f; } u; u.i = raw;
  if (u.f >= 0.f && u.f < 2048.f) return (int)u.f;
  return 2047;
}

// ---------------- K0: x (f32 [32][2048]) -> xt (f32 [2048][32]) transposed
__global__ __launch_bounds__(256) void k_prep(const float* __restrict__ x,
                                              float* __restrict__ xt) {
  int idx = blockIdx.x * 256 + threadIdx.x;   // 65536 total
  int r = idx >> 11, k = idx & 2047;
  xt[k * 32 + r] = x[idx];
}

// ---------------- K1: QKV partial GEMM: part[j][32][3072]
__global__ __launch_bounds__(256) void k_qkv(const float* __restrict__ qw,
                                             const float* __restrict__ kw,
                                             const float* __restrict__ vw,
                                             const float* __restrict__ xt,
                                             float* __restrict__ part, int kc) {
  int colb = blockIdx.x, j = blockIdx.y;
  int n = colb * 256 + threadIdx.x;
  const float* w; int ldw, nn;
  if (colb < 8)       { w = qw; ldw = 2048; nn = n; }
  else if (colb < 10) { w = kw; ldw = 512;  nn = n - 2048; }
  else                { w = vw; ldw = 512;  nn = n - 2560; }
  int k0 = j * kc;
  const float* wp = w + (size_t)k0 * ldw + nn;
  float acc[32];
  #pragma unroll
  for (int r = 0; r < 32; r++) acc[r] = 0.f;
  #pragma unroll 2
  for (int kk = 0; kk < kc; kk++) {
    float wv = wp[(size_t)kk * ldw];
    const float* xr = xt + (size_t)(k0 + kk) * 32;
    #pragma unroll
    for (int r = 0; r < 32; r++) acc[r] = fmaf(xr[r], wv, acc[r]);
  }
  float* po = part + (size_t)j * 32 * NQKV + n;
  #pragma unroll
  for (int r = 0; r < 32; r++) po[(size_t)r * NQKV] = acc[r];
}

// ---------------- K2: attention. grid (8 kv-heads, 32 batches), 1024 threads.
// Lane mapping for K/V streaming: lane = (pp<<4)|d4; 16 lanes (d4) cover the
// 64 dims as float4, 4 positions (pp) per wave instruction. Every K/V element
// is loaded ONCE and used for all 4 rep heads.
__global__ __launch_bounds__(1024) void k_attn(const float* __restrict__ ck,
                                               const float* __restrict__ cv,
                                               const float* __restrict__ part,
                                               float* __restrict__ obt,
                                               const int* __restrict__ spp,
                                               int ks) {
  int h = blockIdx.x, b = blockIdx.y, tid = threadIdx.x;
  int sp = read_sp(spp);                 // 2047; L = sp+1 = 2048

  __shared__ float qraw[384];
  __shared__ __align__(16) float qs[4][64];
  __shared__ __align__(16) float knew[64];
  __shared__ __align__(16) float vnew[64];
  __shared__ __align__(16) float sc[4][2048];
  __shared__ float wredm[16][4];
  __shared__ float wred[16];
  __shared__ float mfin[4];
  __shared__ float inv_[4];
  __shared__ __align__(16) float opart[16][4][64];

  // stage 1: reduce the ks K-split partials for this block's 384 columns
  if (tid < 384) {
    int col;
    if (tid < 256)      col = h * 256 + tid;                 // 4 q heads
    else if (tid < 320) col = 2048 + h * 64 + (tid - 256);   // k
    else                col = 2560 + h * 64 + (tid - 320);   // v
    float s = 0.f;
    for (int j = 0; j < ks; j++) s += part[(size_t)(j * 32 + b) * NQKV + col];
    qraw[tid] = s;
  }
  __syncthreads();

  // stage 2: RoPE (f64 angles) on q (1/8 scale folded) + new k; copy new v
  if (tid < 160) {
    int rr = tid >> 5, i = tid & 31;
    double freq = pow(10000.0, -(double)(2 * i) / 64.0);
    double ang = (double)sp * freq;
    double sd, cd; sincos(ang, &sd, &cd);
    float sn = (float)sd, cs = (float)cd;
    if (rr < 4) {
      float a = qraw[rr * 64 + 2 * i], bq = qraw[rr * 64 + 2 * i + 1];
      qs[rr][2 * i]     = (a * cs - bq * sn) * 0.125f;
      qs[rr][2 * i + 1] = (a * sn + bq * cs) * 0.125f;
    } else {
      float a = qraw[256 + 2 * i], bk = qraw[256 + 2 * i + 1];
      knew[2 * i]     = a * cs - bk * sn;
      knew[2 * i + 1] = a * sn + bk * cs;
    }
  } else if (tid < 224) {
    vnew[tid - 160] = qraw[320 + (tid - 160)];
  }
  __syncthreads();

  int w   = tid >> 6;        // wave 0..15
  int lane = tid & 63;
  int pp  = lane >> 4;       // 0..3  position within quad
  int d4  = lane & 15;       // 0..15 float4 index over 64 dims
  int base = w * 128;        // this wave's 128 positions

  // preload q fragments + new-token rows (lane depends only on d4)
  float4 qv0 = *(const float4*)&qs[0][d4 * 4];
  float4 qv1 = *(const float4*)&qs[1][d4 * 4];
  float4 qv2 = *(const float4*)&qs[2][d4 * 4];
  float4 qv3 = *(const float4*)&qs[3][d4 * 4];
  float4 kn4 = *(const float4*)&knew[d4 * 4];
  float4 vn4 = *(const float4*)&vnew[d4 * 4];

  // pass 1: scores. One K row read per position, shared by all 4 rep heads.
  const float* kb = ck + ((size_t)b * 2048 * 8 + h) * 64;
  float lm0 = -1e30f, lm1 = -1e30f, lm2 = -1e30f, lm3 = -1e30f;
  #pragma unroll 4
  for (int i = 0; i < 32; i++) {
    int p = base + i * 4 + pp;
    float4 k4 = *(const float4*)(kb + (size_t)p * 512 + d4 * 4);
    if (p == sp) k4 = kn4;   // override stale cached row (branchless select)
    float s0 = qv0.x * k4.x + qv0.y * k4.y + qv0.z * k4.z + qv0.w * k4.w;
    float s1 = qv1.x * k4.x + qv1.y * k4.y + qv1.z * k4.z + qv1.w * k4.w;
    float s2 = qv2.x * k4.x + qv2.y * k4.y + qv2.z * k4.z + qv2.w * k4.w;
    float s3 = qv3.x * k4.x + qv3.y * k4.y + qv3.z * k4.z + qv3.w * k4.w;
    #pragma unroll
    for (int off = 1; off <= 8; off <<= 1) {   // reduce over d4 (16 lanes)
      s0 += __shfl_xor(s0, off);
      s1 += __shfl_xor(s1, off);
      s2 += __shfl_xor(s2, off);
      s3 += __shfl_xor(s3, off);
    }
    lm0 = fmaxf(lm0, s0); lm1 = fmaxf(lm1, s1);
    lm2 = fmaxf(lm2, s2); lm3 = fmaxf(lm3, s3);
    float sv = (d4 == 0) ? s0 : (d4 == 1) ? s1 : (d4 == 2) ? s2 : s3;
    if (d4 < 4) sc[d4][p] = sv;
  }
  // wave max over pp groups (values already uniform over d4)
  lm0 = fmaxf(lm0, __shfl_xor(lm0, 16)); lm0 = fmaxf(lm0, __shfl_xor(lm0, 32));
  lm1 = fmaxf(lm1, __shfl_xor(lm1, 16)); lm1 = fmaxf(lm1, __shfl_xor(lm1, 32));
  lm2 = fmaxf(lm2, __shfl_xor(lm2, 16)); lm2 = fmaxf(lm2, __shfl_xor(lm2, 32));
  lm3 = fmaxf(lm3, __shfl_xor(lm3, 16)); lm3 = fmaxf(lm3, __shfl_xor(lm3, 32));
  if (lane == 0) {
    wredm[w][0] = lm0; wredm[w][1] = lm1; wredm[w][2] = lm2; wredm[w][3] = lm3;
  }
  __syncthreads();
  if (tid < 4) {
    float m = wredm[0][tid];
    #pragma unroll
    for (int w2 = 1; w2 < 16; w2++) m = fmaxf(m, wredm[w2][tid]);
    mfin[tid] = m;
  }
  __syncthreads();

  // softmax exp + sum (per rep head r; its 4 waves are 4r..4r+3)
  {
    int r = tid >> 8;
    int t = tid & 255;
    float m = mfin[r];
    float lsum = 0.f;
    #pragma unroll
    for (int jj = 0; jj < 8; jj++) {
      float e = __expf(sc[r][jj * 256 + t] - m);
      lsum += e;
      sc[r][jj * 256 + t] = e;
    }
    #pragma unroll
    for (int off = 32; off > 0; off >>= 1) lsum += __shfl_xor(lsum, off);
    if ((tid & 63) == 0) wred[w] = lsum;
  }
  __syncthreads();
  if (tid < 4)
    inv_[tid] = 1.0f / (wred[tid * 4 + 0] + wred[tid * 4 + 1] +
                        wred[tid * 4 + 2] + wred[tid * 4 + 3]);
  __syncthreads();

  // pass 2: o[r][d] += e[r][p] * v[p][d]. One V row read per position,
  // shared by all 4 rep heads. acc float4 per rep head.
  const float* vb = cv + ((size_t)b * 2048 * 8 + h) * 64;
  float4 a0 = {0,0,0,0}, a1 = {0,0,0,0}, a2 = {0,0,0,0}, a3 = {0,0,0,0};
  #pragma unroll 4
  for (int i = 0; i < 32; i++) {
    int p = base + i * 4 + pp;
    float4 v4 = *(const float4*)(vb + (size_t)p * 512 + d4 * 4);
    if (p == sp) v4 = vn4;
    float e0 = sc[0][p], e1 = sc[1][p], e2 = sc[2][p], e3 = sc[3][p];
    a0.x = fmaf(e0, v4.x, a0.x); a0.y = fmaf(e0, v4.y, a0.y);
    a0.z = fmaf(e0, v4.z, a0.z); a0.w = fmaf(e0, v4.w, a0.w);
    a1.x = fmaf(e1, v4.x, a1.x); a1.y = fmaf(e1, v4.y, a1.y);
    a1.z = fmaf(e1, v4.z, a1.z); a1.w = fmaf(e1, v4.w, a1.w);
    a2.x = fmaf(e2, v4.x, a2.x); a2.y = fmaf(e2, v4.y, a2.y);
    a2.z = fmaf(e2, v4.z, a2.z); a2.w = fmaf(e2, v4.w, a2.w);
    a3.x = fmaf(e3, v4.x, a3.x); a3.y = fmaf(e3, v4.y, a3.y);
    a3.z = fmaf(e3, v4.z, a3.z); a3.w = fmaf(e3, v4.w, a3.w);
  }
  // reduce over pp groups (masks 16, 32) for each component
  #pragma unroll
  for (int off = 16; off <= 32; off <<= 1) {
    a0.x += __shfl_xor(a0.x, off); a0.y += __shfl_xor(a0.y, off);
    a0.z += __shfl_xor(a0.z, off); a0.w += __shfl_xor(a0.w, off);
    a1.x += __shfl_xor(a1.x, off); a1.y += __shfl_xor(a1.y, off);
    a1.z += __shfl_xor(a1.z, off); a1.w += __shfl_xor(a1.w, off);
    a2.x += __shfl_xor(a2.x, off); a2.y += __shfl_xor(a2.y, off);
    a2.z += __shfl_xor(a2.z, off); a2.w += __shfl_xor(a2.w, off);
    a3.x += __shfl_xor(a3.x, off); a3.y += __shfl_xor(a3.y, off);
    a3.z += __shfl_xor(a3.z, off); a3.w += __shfl_xor(a3.w, off);
  }
  if (pp == 0) {
    *(float4*)&opart[w][0][d4 * 4] = a0;
    *(float4*)&opart[w][1][d4 * 4] = a1;
    *(float4*)&opart[w][2][d4 * 4] = a2;
    *(float4*)&opart[w][3][d4 * 4] = a3;
  }
  __syncthreads();
  if (tid < 256) {
    int rr = tid >> 6, dd = tid & 63;
    float o = 0.f;
    #pragma unroll
    for (int w2 = 0; w2 < 16; w2++) o += opart[w2][rr][dd];
    o *= inv_[rr];
    int col = (h * 4 + rr) * 64 + dd;
    obt[(size_t)col * 32 + b] = o;                 // transposed for k_oproj
  }
}

// ---------------- K3: O partial GEMM: part[j][32][2048] (aliases part_qkv)
__global__ __launch_bounds__(256) void k_oproj(const float* __restrict__ ow,
                                               const float* __restrict__ obt,
                                               float* __restrict__ part, int kc) {
  int colb = blockIdx.x, j = blockIdx.y;
  int n = colb * 256 + threadIdx.x;
  int k0 = j * kc;
  const float* wp = ow + (size_t)k0 * 2048 + n;
  float acc[32];
  #pragma unroll
  for (int r = 0; r < 32; r++) acc[r] = 0.f;
  #pragma unroll 2
  for (int kk = 0; kk < kc; kk++) {
    float wv = wp[(size_t)kk * 2048];
    const float* xr = obt + (size_t)(k0 + kk) * 32;
    #pragma unroll
    for (int r = 0; r < 32; r++) acc[r] = fmaf(xr[r], wv, acc[r]);
  }
  float* po = part + (size_t)j * 32 * 2048 + n;
  #pragma unroll
  for (int r = 0; r < 32; r++) po[(size_t)r * 2048] = acc[r];
}

// ---------------- K4: reduce K-split partials -> f32 output
__global__ __launch_bounds__(256) void k_finish(const float* __restrict__ part,
                                                float* __restrict__ out, int ks) {
  int idx = blockIdx.x * 256 + threadIdx.x;  // 65536 = 32*2048, b*2048+n
  float s = 0.f;
  for (int j = 0; j < ks; j++) s += part[(size_t)j * 65536 + idx];
  out[idx] = s;                              // FLOAT32 output
}

extern "C" void kernel_launch(void* const* d_in, const int* in_sizes, int n_in,
                              void* d_out, int out_size, void* d_ws, size_t ws_size,
                              hipStream_t stream) {
  const float* x  = (const float*)d_in[0];
  const float* qw = (const float*)d_in[1];
  const float* kw = (const float*)d_in[2];
  const float* vw = (const float*)d_in[3];
  const float* ow = (const float*)d_in[4];
  const float* ck = (const float*)d_in[5];
  const float* cv = (const float*)d_in[6];
  const int*   sp = (n_in >= 8) ? (const int*)d_in[7] : nullptr;

  // Pick K-split so workspace fits: (131072 + ks*98304) f32.
  int ks = 1;
  {
    const int cands[4] = {16, 8, 4, 2};
    for (int i = 0; i < 4; i++) {
      if ((size_t)(131072 + (size_t)cands[i] * 98304) * 4 <= ws_size) { ks = cands[i]; break; }
    }
  }
  int kc = 2048 / ks;

  float* ws   = (float*)d_ws;
  float* xt   = ws;                          // 65536 f32
  float* part = xt + 65536;                  // ks*98304 f32 (QKV partials)
  float* obt  = part + (size_t)ks * 98304;   // 65536 f32
  float* part_out = part;                    // reuse after k_attn

  k_prep  <<<256,          256,  0, stream>>>(x, xt);
  k_qkv   <<<dim3(12, ks), 256,  0, stream>>>(qw, kw, vw, xt, part, kc);
  k_attn  <<<dim3(8, 32),  1024, 0, stream>>>(ck, cv, part, obt, sp, ks);
  k_oproj <<<dim3(8, ks),  256,  0, stream>>>(ow, obt, part_out, kc);
  k_finish<<<256,          256,  0, stream>>>(part_out, (float*)d_out, ks);
}